// Round 9
// baseline (133.475 us; speedup 1.0000x reference)
//
#include <hip/hip_runtime.h>

#define G 128
#define D_OUT 16
#define BIN_SHIFT 3              // 8 cells per bin per dim
#define NBINS (16 * 16 * 16)     // 4096
#define NBLK 256                 // blocks for hist/scatter passes
#define QPB 1024                 // queries per interp chunk
#define MAXCHUNK 5120            // >= NBINS + NQUERY/QPB
#define PBLK 768                 // persistent interp blocks (3 per CU)
#define REGION_SLOTS (81 * 36)   // 2916 ushort4 slots per region

typedef float f32x4 __attribute__((ext_vector_type(4)));

// ---------- shared helpers ----------

__device__ __forceinline__ void stage_grids(const float* __restrict__ xs0,
                                            const float* __restrict__ xs1,
                                            const float* __restrict__ xs2,
                                            float (*sxs)[G], int tid, int nthreads)
{
    for (int i = tid; i < 3 * G; i += nthreads) {
        float v;
        if (i < G)            v = xs0[i];
        else if (i < 2 * G)   v = xs1[i - G];
        else                  v = xs2[i - 2 * G];
        (&sxs[0][0])[i] = v;
    }
}

__device__ __forceinline__ void search1(const float* __restrict__ g, float v,
                                        int& li, float& t)
{
    v = fminf(fmaxf(v, g[0]), g[G - 1]);
    int idx = 0;
    #pragma unroll
    for (int s = 64; s >= 1; s >>= 1) {
        int cand = idx + s;
        if (g[cand] <= v) idx = cand;
    }
    if (idx > G - 2) idx = G - 2;
    li = idx;
    t  = (v - g[idx]) / (g[idx + 1] - g[idx]);
}

__device__ __forceinline__ int bin_of(int li0, int li1, int li2)
{
    return ((li0 >> BIN_SHIFT) << 8) | ((li1 >> BIN_SHIFT) << 4) | (li2 >> BIN_SHIFT);
}

__device__ __forceinline__ unsigned short f2bf(float f)
{
    unsigned int u = __float_as_uint(f);
    u += 0x7FFFu + ((u >> 16) & 1u);
    return (unsigned short)(u >> 16);
}

__device__ __forceinline__ float bf2f(unsigned short h)
{
    return __uint_as_float((unsigned int)h << 16);
}

// slot s of a region: row = s/36 (l0*9+l1), f4 = s%36 (cc*4+ch)
__device__ __forceinline__ const f32x4* slot_src(const float* __restrict__ y,
                                                 int o0, int o1, int o2, int s)
{
    const int row = s / 36;
    const int f4  = s - row * 36;
    const int l0 = row / 9, l1 = row - l0 * 9;
    const int cc = f4 >> 2, ch = f4 & 3;
    const int g0 = min(o0 + l0, G - 1);
    const int g1 = min(o1 + l1, G - 1);
    const int g2 = min(o2 + cc, G - 1);
    return (const f32x4*)(y + ((((g0 << 7) | g1) << 7) | g2) * D_OUT + (ch << 2));
}

// ---------- pass 1: per-block LDS histogram ----------

__global__ __launch_bounds__(256) void hist_kernel(
    const float* __restrict__ x,
    const float* __restrict__ xs0, const float* __restrict__ xs1, const float* __restrict__ xs2,
    unsigned int* __restrict__ counts,   // [NBLK][NBINS]
    int n, int qpb)
{
    __shared__ float sxs[3][G];
    __shared__ unsigned int hist[NBINS];
    const int tid = threadIdx.x, blk = blockIdx.x;

    stage_grids(xs0, xs1, xs2, sxs, tid, 256);
    for (int i = tid; i < NBINS; i += 256) hist[i] = 0u;
    __syncthreads();

    const int q0 = blk * qpb, q1 = min(n, q0 + qpb);
    for (int q = q0 + tid; q < q1; q += 256) {
        int li[3]; float t;
        #pragma unroll
        for (int d = 0; d < 3; ++d) search1(sxs[d], x[q * 3 + d], li[d], t);
        atomicAdd(&hist[bin_of(li[0], li[1], li[2])], 1u);
    }
    __syncthreads();

    for (int i = tid; i < NBINS; i += 256)
        counts[(size_t)blk * NBINS + i] = hist[i];
}

// ---------- pass 2a: per-bin exclusive scan across block rows ----------

__global__ __launch_bounds__(256) void scan_block_kernel(
    const unsigned int* __restrict__ counts,
    unsigned int* __restrict__ offs,
    unsigned int* __restrict__ totals)
{
    __shared__ unsigned int sd[NBLK];
    const int b = blockIdx.x, k = threadIdx.x;
    const unsigned int v = counts[(size_t)k * NBINS + b];
    sd[k] = v;
    __syncthreads();
    for (int off = 1; off < NBLK; off <<= 1) {
        unsigned int t = sd[k];
        unsigned int a = (k >= off) ? sd[k - off] : 0u;
        __syncthreads();
        sd[k] = t + a;
        __syncthreads();
    }
    const unsigned int incl = sd[k];
    offs[(size_t)k * NBINS + b] = incl - v;
    if (k == NBLK - 1) totals[b] = incl;
}

// ---------- pass 2b: scan totals + chunk work list + zero 8 counters ----------

__global__ __launch_bounds__(1024) void scan_totals_kernel(
    const unsigned int* __restrict__ totals,
    unsigned int* __restrict__ bin_base,   // [NBINS+1]
    unsigned int* __restrict__ map,        // [MAXCHUNK] -> (bin<<8)|chunk
    unsigned int* __restrict__ nchunks,    // [1]
    unsigned int* __restrict__ counters)   // [8] per-XCD work counters
{
    __shared__ unsigned int sq[1024], sc[1024];
    const int t = threadIdx.x;
    if (t < 8) counters[t] = 0u;
    uint4 c = ((const uint4*)totals)[t];
    uint4 h;
    h.x = (c.x + QPB - 1) / QPB;
    h.y = (c.y + QPB - 1) / QPB;
    h.z = (c.z + QPB - 1) / QPB;
    h.w = (c.w + QPB - 1) / QPB;
    const unsigned int sum_q = c.x + c.y + c.z + c.w;
    const unsigned int sum_c = h.x + h.y + h.z + h.w;
    sq[t] = sum_q; sc[t] = sum_c;
    __syncthreads();
    for (int off = 1; off < 1024; off <<= 1) {
        unsigned int vq = sq[t], vc = sc[t];
        unsigned int aq = (t >= off) ? sq[t - off] : 0u;
        unsigned int ac = (t >= off) ? sc[t - off] : 0u;
        __syncthreads();
        sq[t] = vq + aq; sc[t] = vc + ac;
        __syncthreads();
    }
    const unsigned int eq = sq[t] - sum_q;
    const unsigned int ec = sc[t] - sum_c;

    uint4 qb;
    qb.x = eq;
    qb.y = qb.x + c.x;
    qb.z = qb.y + c.y;
    qb.w = qb.z + c.z;
    ((uint4*)bin_base)[t] = qb;
    if (t == 1023) {
        bin_base[NBINS] = sq[1023];
        nchunks[0] = sc[1023];
    }

    unsigned int cb = ec;
    unsigned int hh[4] = { h.x, h.y, h.z, h.w };
    #pragma unroll
    for (int k = 0; k < 4; ++k) {
        const unsigned int binid = ((unsigned int)t << 2) | k;
        for (unsigned int j = 0; j < hh[k]; ++j)
            map[cb + j] = (binid << 8) | j;
        cb += hh[k];
    }
}

// ---------- pass 3: scatter; payload = (t0,t1,t2, pack(localcell,q)) ----------

__global__ __launch_bounds__(256) void scatter_kernel(
    const float* __restrict__ x,
    const float* __restrict__ xs0, const float* __restrict__ xs1, const float* __restrict__ xs2,
    const unsigned int* __restrict__ offs,
    const unsigned int* __restrict__ bin_base,
    float4* __restrict__ payload,
    int n, int qpb)
{
    __shared__ float sxs[3][G];
    __shared__ unsigned int base[NBINS];
    const int tid = threadIdx.x, blk = blockIdx.x;

    stage_grids(xs0, xs1, xs2, sxs, tid, 256);
    for (int i = tid; i < NBINS; i += 256)
        base[i] = bin_base[i] + offs[(size_t)blk * NBINS + i];
    __syncthreads();

    const int q0 = blk * qpb, q1 = min(n, q0 + qpb);
    for (int q = q0 + tid; q < q1; q += 256) {
        int li0, li1, li2; float t0, t1, t2;
        search1(sxs[0], x[q * 3 + 0], li0, t0);
        search1(sxs[1], x[q * 3 + 1], li1, t1);
        search1(sxs[2], x[q * 3 + 2], li2, t2);
        unsigned int slot = atomicAdd(&base[bin_of(li0, li1, li2)], 1u);
        const unsigned int bits = ((unsigned int)(li0 & 7) << 26)
                                | ((unsigned int)(li1 & 7) << 23)
                                | ((unsigned int)(li2 & 7) << 20)
                                | (unsigned int)q;
        payload[slot] = make_float4(t0, t1, t2, __uint_as_float(bits));
    }
}

// ---------- pass 4: persistent, double-buffered, async-staged interp ----------
// 512 threads, 2 x 23.3 KB bf16 regions -> 3 blocks/CU, 24 waves/CU.
// Per chunk: {grab next-next, issue next-region loads to regs, serve current
// from LDS, convert+ds_write next region} then ONE barrier.

__global__ __launch_bounds__(512) void interp_staged_kernel(
    const float4* __restrict__ payload,
    const float* __restrict__ y,
    const unsigned int* __restrict__ bin_base,
    const unsigned int* __restrict__ map,
    const unsigned int* __restrict__ nchunks,
    unsigned int* __restrict__ counters,   // [8]
    float* __restrict__ out)
{
    __shared__ unsigned short region[2][REGION_SLOTS * 4];  // 2 x 23,328 B
    __shared__ unsigned int s_nxt[2];
    const int tid = threadIdx.x;
    const unsigned int nch = nchunks[0];
    // 8 contiguous chunk ranges; block's range keyed by bid&7 (locality
    // heuristic only — all 8 ranges always have PBLK/8 blocks => correct
    // regardless of actual XCD mapping).
    const unsigned int rng = blockIdx.x & 7u;
    const unsigned int per = (nch + 7u) >> 3;
    const unsigned int lo  = rng * per;
    const unsigned int hi  = min(nch, lo + per);
    const int cg = (tid & 3) << 2;

    if (tid == 0) {
        unsigned int c0 = lo + atomicAdd(&counters[rng], 1u);
        s_nxt[0] = (c0 < hi) ? map[c0] : 0xFFFFFFFFu;
        unsigned int c1 = lo + atomicAdd(&counters[rng], 1u);
        s_nxt[1] = (c1 < hi) ? map[c1] : 0xFFFFFFFFu;
    }
    __syncthreads();
    unsigned int cur_info = s_nxt[0];
    if (cur_info == 0xFFFFFFFFu) return;

    // prologue: stage chunk 0 directly
    {
        const unsigned int bin = cur_info >> 8;
        const int o0 = (int)((bin >> 8) & 15u) << 3;
        const int o1 = (int)((bin >> 4) & 15u) << 3;
        const int o2 = (int)(bin & 15u) << 3;
        for (int s = tid; s < REGION_SLOTS; s += 512) {
            const f32x4 v = *slot_src(y, o0, o1, o2, s);
            ushort4 hv;
            hv.x = f2bf(v.x); hv.y = f2bf(v.y); hv.z = f2bf(v.z); hv.w = f2bf(v.w);
            *(ushort4*)&region[0][s * 4] = hv;
        }
    }
    __syncthreads();   // region[0] ready; s_nxt[1] published

    int buf = 0;
    unsigned int parity = 0;
    for (;;) {
        const unsigned int nxt_info = s_nxt[parity ^ 1u];
        if (tid == 0) {
            unsigned int c = lo + atomicAdd(&counters[rng], 1u);
            s_nxt[parity] = (c < hi) ? map[c] : 0xFFFFFFFFu;
        }

        // ---- STAGE_LOAD: issue next region's global loads into registers ----
        const bool have_nxt = (nxt_info != 0xFFFFFFFFu);
        f32x4 st0, st1, st2, st3, st4, st5;
        if (have_nxt) {
            const unsigned int nbin = nxt_info >> 8;
            const int n0 = (int)((nbin >> 8) & 15u) << 3;
            const int n1 = (int)((nbin >> 4) & 15u) << 3;
            const int n2 = (int)(nbin & 15u) << 3;
            const int s0 = tid;
            st0 = *slot_src(y, n0, n1, n2, s0);
            st1 = *slot_src(y, n0, n1, n2, s0 + 512);
            st2 = *slot_src(y, n0, n1, n2, s0 + 1024);
            st3 = *slot_src(y, n0, n1, n2, s0 + 1536);
            st4 = *slot_src(y, n0, n1, n2, s0 + 2048);
            if (s0 + 2560 < REGION_SLOTS) st5 = *slot_src(y, n0, n1, n2, s0 + 2560);
        }

        // ---- SERVE current chunk from LDS ----
        {
            const unsigned int bin = cur_info >> 8;
            const unsigned int chk = cur_info & 255u;
            const unsigned int qs = bin_base[bin] + chk * QPB;
            const unsigned int qe = min(bin_base[bin + 1], qs + QPB);
            const unsigned short* reg = region[buf];

            for (unsigned int i = qs + (tid >> 2); i < qe; i += 128) {
                const float4 p = payload[i];
                const unsigned int bits = __float_as_uint(p.w);
                const unsigned int q   = bits & 0xFFFFFu;
                const unsigned int lc0 = (bits >> 26) & 7u;
                const unsigned int lc1 = (bits >> 23) & 7u;
                const unsigned int lc2 = (bits >> 20) & 7u;

                const float t0 = p.x, t1 = p.y, t2 = p.z;
                const float u0 = 1.f - t0, u1 = 1.f - t1, u2 = 1.f - t2;

                const int base = (int)((lc0 * 9u + lc1) * 9u + lc2) * D_OUT + cg;
                const int d2 = D_OUT, d1 = 9 * D_OUT, d0 = 81 * D_OUT;

                const ushort4 h000 = *(const ushort4*)&reg[base];
                const ushort4 h001 = *(const ushort4*)&reg[base + d2];
                const ushort4 h010 = *(const ushort4*)&reg[base + d1];
                const ushort4 h011 = *(const ushort4*)&reg[base + d1 + d2];
                const ushort4 h100 = *(const ushort4*)&reg[base + d0];
                const ushort4 h101 = *(const ushort4*)&reg[base + d0 + d2];
                const ushort4 h110 = *(const ushort4*)&reg[base + d0 + d1];
                const ushort4 h111 = *(const ushort4*)&reg[base + d0 + d1 + d2];

                const float w000 = u0 * u1 * u2, w001 = u0 * u1 * t2;
                const float w010 = u0 * t1 * u2, w011 = u0 * t1 * t2;
                const float w100 = t0 * u1 * u2, w101 = t0 * u1 * t2;
                const float w110 = t0 * t1 * u2, w111 = t0 * t1 * t2;

                f32x4 acc;
                #pragma unroll
                for (int k = 0; k < 4; ++k) {
                    acc[k] = w000 * bf2f((&h000.x)[k]) + w001 * bf2f((&h001.x)[k])
                           + w010 * bf2f((&h010.x)[k]) + w011 * bf2f((&h011.x)[k])
                           + w100 * bf2f((&h100.x)[k]) + w101 * bf2f((&h101.x)[k])
                           + w110 * bf2f((&h110.x)[k]) + w111 * bf2f((&h111.x)[k]);
                }
                __builtin_nontemporal_store(acc, (f32x4*)(out + (size_t)q * D_OUT + cg));
            }
        }

        // ---- STAGE_WRITE: convert + ds_write the prefetched region ----
        if (have_nxt) {
            unsigned short* dst = region[buf ^ 1];
            const int s0 = tid;
            ushort4 hv;
            hv.x = f2bf(st0.x); hv.y = f2bf(st0.y); hv.z = f2bf(st0.z); hv.w = f2bf(st0.w);
            *(ushort4*)&dst[s0 * 4] = hv;
            hv.x = f2bf(st1.x); hv.y = f2bf(st1.y); hv.z = f2bf(st1.z); hv.w = f2bf(st1.w);
            *(ushort4*)&dst[(s0 + 512) * 4] = hv;
            hv.x = f2bf(st2.x); hv.y = f2bf(st2.y); hv.z = f2bf(st2.z); hv.w = f2bf(st2.w);
            *(ushort4*)&dst[(s0 + 1024) * 4] = hv;
            hv.x = f2bf(st3.x); hv.y = f2bf(st3.y); hv.z = f2bf(st3.z); hv.w = f2bf(st3.w);
            *(ushort4*)&dst[(s0 + 1536) * 4] = hv;
            hv.x = f2bf(st4.x); hv.y = f2bf(st4.y); hv.z = f2bf(st4.z); hv.w = f2bf(st4.w);
            *(ushort4*)&dst[(s0 + 2048) * 4] = hv;
            if (s0 + 2560 < REGION_SLOTS) {
                hv.x = f2bf(st5.x); hv.y = f2bf(st5.y); hv.z = f2bf(st5.z); hv.w = f2bf(st5.w);
                *(ushort4*)&dst[(s0 + 2560) * 4] = hv;
            }
        } else {
            break;
        }
        __syncthreads();   // next region ready; serve of old buf complete
        cur_info = nxt_info;
        buf ^= 1;
        parity ^= 1u;
    }
}

// ---------- fallback: direct kernel (known-good R1) ----------

__global__ __launch_bounds__(256) void interp3d_kernel(
    const float* __restrict__ x, const float* __restrict__ y,
    const float* __restrict__ xs0, const float* __restrict__ xs1, const float* __restrict__ xs2,
    float* __restrict__ out, int nquery)
{
    __shared__ float sxs[3][G];
    stage_grids(xs0, xs1, xs2, sxs, threadIdx.x, 256);
    __syncthreads();

    const int q = blockIdx.x * 64 + (threadIdx.x >> 2);
    if (q >= nquery) return;
    const int cg = (threadIdx.x & 3) * 4;

    int li[3]; float t[3];
    #pragma unroll
    for (int d = 0; d < 3; ++d) search1(sxs[d], x[q * 3 + d], li[d], t[d]);

    const float w0[3] = { 1.f - t[0], 1.f - t[1], 1.f - t[2] };
    const float w1[3] = { t[0], t[1], t[2] };

    float4 acc = make_float4(0.f, 0.f, 0.f, 0.f);
    #pragma unroll
    for (int e = 0; e < 8; ++e) {
        const int e0 = (e >> 2) & 1, e1 = (e >> 1) & 1, e2 = e & 1;
        const float w = (e0 ? w1[0] : w0[0]) * (e1 ? w1[1] : w0[1]) * (e2 ? w1[2] : w0[2]);
        const int idx = ((li[0] + e0) * G + (li[1] + e1)) * G + (li[2] + e2);
        const float4 v = *(const float4*)(y + (size_t)idx * D_OUT + cg);
        acc.x += w * v.x; acc.y += w * v.y; acc.z += w * v.z; acc.w += w * v.w;
    }
    *(float4*)(out + (size_t)q * D_OUT + cg) = acc;
}

extern "C" void kernel_launch(void* const* d_in, const int* in_sizes, int n_in,
                              void* d_out, int out_size, void* d_ws, size_t ws_size,
                              hipStream_t stream) {
    const float* x   = (const float*)d_in[0];
    const float* y   = (const float*)d_in[1];
    const float* xs0 = (const float*)d_in[2];
    const float* xs1 = (const float*)d_in[3];
    const float* xs2 = (const float*)d_in[4];
    float* out = (float*)d_out;

    const int nquery = in_sizes[0] / 3;

    const size_t counts_elems = (size_t)NBLK * NBINS;
    const size_t need = (size_t)nquery * sizeof(float4)
                      + (2 * counts_elems + NBINS + (NBINS + 1) + MAXCHUNK + 16) * sizeof(unsigned int);
    if (ws_size < need || nquery > (1 << 20)) {
        const int blocks = (nquery + 63) / 64;
        hipLaunchKernelGGL(interp3d_kernel, dim3(blocks), dim3(256), 0, stream,
                           x, y, xs0, xs1, xs2, out, nquery);
        return;
    }

    float4*       payload  = (float4*)d_ws;
    unsigned int* counts   = (unsigned int*)(payload + nquery);
    unsigned int* offs     = counts + counts_elems;
    unsigned int* totals   = offs + counts_elems;
    unsigned int* bin_base = totals + NBINS;
    unsigned int* map      = bin_base + (NBINS + 1);
    unsigned int* nchunks  = map + MAXCHUNK;
    unsigned int* counters = nchunks + 1;   // [8]

    const int qpb = (nquery + NBLK - 1) / NBLK;

    hipLaunchKernelGGL(hist_kernel, dim3(NBLK), dim3(256), 0, stream,
                       x, xs0, xs1, xs2, counts, nquery, qpb);
    hipLaunchKernelGGL(scan_block_kernel, dim3(NBINS), dim3(NBLK), 0, stream,
                       counts, offs, totals);
    hipLaunchKernelGGL(scan_totals_kernel, dim3(1), dim3(1024), 0, stream,
                       totals, bin_base, map, nchunks, counters);
    hipLaunchKernelGGL(scatter_kernel, dim3(NBLK), dim3(256), 0, stream,
                       x, xs0, xs1, xs2, offs, bin_base, payload, nquery, qpb);
    hipLaunchKernelGGL(interp_staged_kernel, dim3(PBLK), dim3(512), 0, stream,
                       payload, y, bin_base, map, nchunks, counters, out);
}

// Round 10
// 104.110 us; speedup vs baseline: 1.2821x; 1.2821x over previous
//
#include <hip/hip_runtime.h>

#define G 128
#define D_OUT 16
#define BIN_SHIFT 3              // 8 cells per bin per dim
#define NBINS (16 * 16 * 16)     // 4096
#define NBLK 256                 // blocks for hist/scatter passes
#define QPB 64                   // queries per interp chunk (= 1 block iteration)
#define MAXCHUNK 20480           // >= NBINS + NQUERY/QPB, multiple of 8

typedef float f32x4 __attribute__((ext_vector_type(4)));

// ---------- shared helpers ----------

__device__ __forceinline__ void stage_grids(const float* __restrict__ xs0,
                                            const float* __restrict__ xs1,
                                            const float* __restrict__ xs2,
                                            float (*sxs)[G], int tid, int nthreads)
{
    for (int i = tid; i < 3 * G; i += nthreads) {
        float v;
        if (i < G)            v = xs0[i];
        else if (i < 2 * G)   v = xs1[i - G];
        else                  v = xs2[i - 2 * G];
        (&sxs[0][0])[i] = v;
    }
}

__device__ __forceinline__ void search1(const float* __restrict__ g, float v,
                                        int& li, float& t)
{
    v = fminf(fmaxf(v, g[0]), g[G - 1]);
    int idx = 0;
    #pragma unroll
    for (int s = 64; s >= 1; s >>= 1) {
        int cand = idx + s;
        if (g[cand] <= v) idx = cand;
    }
    if (idx > G - 2) idx = G - 2;
    li = idx;
    t  = (v - g[idx]) / (g[idx + 1] - g[idx]);
}

__device__ __forceinline__ int bin_of(int li0, int li1, int li2)
{
    return ((li0 >> BIN_SHIFT) << 8) | ((li1 >> BIN_SHIFT) << 4) | (li2 >> BIN_SHIFT);
}

// ---------- pass 1: per-block LDS histogram ----------

__global__ __launch_bounds__(256) void hist_kernel(
    const float* __restrict__ x,
    const float* __restrict__ xs0, const float* __restrict__ xs1, const float* __restrict__ xs2,
    unsigned int* __restrict__ counts,   // [NBLK][NBINS]
    int n, int qpb)
{
    __shared__ float sxs[3][G];
    __shared__ unsigned int hist[NBINS];
    const int tid = threadIdx.x, blk = blockIdx.x;

    stage_grids(xs0, xs1, xs2, sxs, tid, 256);
    for (int i = tid; i < NBINS; i += 256) hist[i] = 0u;
    __syncthreads();

    const int q0 = blk * qpb, q1 = min(n, q0 + qpb);
    for (int q = q0 + tid; q < q1; q += 256) {
        int li[3]; float t;
        #pragma unroll
        for (int d = 0; d < 3; ++d) search1(sxs[d], x[q * 3 + d], li[d], t);
        atomicAdd(&hist[bin_of(li[0], li[1], li[2])], 1u);
    }
    __syncthreads();

    for (int i = tid; i < NBINS; i += 256)
        counts[(size_t)blk * NBINS + i] = hist[i];
}

// ---------- pass 2a: per-bin exclusive scan across block rows ----------

__global__ __launch_bounds__(256) void scan_block_kernel(
    const unsigned int* __restrict__ counts,
    unsigned int* __restrict__ offs,
    unsigned int* __restrict__ totals)
{
    __shared__ unsigned int sd[NBLK];
    const int b = blockIdx.x, k = threadIdx.x;
    const unsigned int v = counts[(size_t)k * NBINS + b];
    sd[k] = v;
    __syncthreads();
    for (int off = 1; off < NBLK; off <<= 1) {
        unsigned int t = sd[k];
        unsigned int a = (k >= off) ? sd[k - off] : 0u;
        __syncthreads();
        sd[k] = t + a;
        __syncthreads();
    }
    const unsigned int incl = sd[k];
    offs[(size_t)k * NBINS + b] = incl - v;
    if (k == NBLK - 1) totals[b] = incl;
}

// ---------- pass 2b: scan totals + build chunk work list ----------
// map entry: bin (12 bits) | chunk_idx << 12

__global__ __launch_bounds__(1024) void scan_totals_kernel(
    const unsigned int* __restrict__ totals,
    unsigned int* __restrict__ bin_base,   // [NBINS+1]
    unsigned int* __restrict__ map,        // [MAXCHUNK]
    unsigned int* __restrict__ nchunks)    // [1]
{
    __shared__ unsigned int sq[1024], sc[1024];
    const int t = threadIdx.x;
    uint4 c = ((const uint4*)totals)[t];
    uint4 h;
    h.x = (c.x + QPB - 1) / QPB;
    h.y = (c.y + QPB - 1) / QPB;
    h.z = (c.z + QPB - 1) / QPB;
    h.w = (c.w + QPB - 1) / QPB;
    const unsigned int sum_q = c.x + c.y + c.z + c.w;
    const unsigned int sum_c = h.x + h.y + h.z + h.w;
    sq[t] = sum_q; sc[t] = sum_c;
    __syncthreads();
    for (int off = 1; off < 1024; off <<= 1) {
        unsigned int vq = sq[t], vc = sc[t];
        unsigned int aq = (t >= off) ? sq[t - off] : 0u;
        unsigned int ac = (t >= off) ? sc[t - off] : 0u;
        __syncthreads();
        sq[t] = vq + aq; sc[t] = vc + ac;
        __syncthreads();
    }
    const unsigned int eq = sq[t] - sum_q;
    const unsigned int ec = sc[t] - sum_c;

    uint4 qb;
    qb.x = eq;
    qb.y = qb.x + c.x;
    qb.z = qb.y + c.y;
    qb.w = qb.z + c.z;
    ((uint4*)bin_base)[t] = qb;
    if (t == 1023) {
        bin_base[NBINS] = sq[1023];
        nchunks[0] = sc[1023];
    }

    unsigned int cb = ec;
    unsigned int hh[4] = { h.x, h.y, h.z, h.w };
    #pragma unroll
    for (int k = 0; k < 4; ++k) {
        const unsigned int binid = ((unsigned int)t << 2) | k;
        for (unsigned int j = 0; j < hh[k]; ++j)
            map[cb + j] = binid | (j << 12);
        cb += hh[k];
    }
}

// ---------- pass 3: scatter; payload = (t0,t1,t2, q | lc<<20) ----------

__global__ __launch_bounds__(256) void scatter_kernel(
    const float* __restrict__ x,
    const float* __restrict__ xs0, const float* __restrict__ xs1, const float* __restrict__ xs2,
    const unsigned int* __restrict__ offs,
    const unsigned int* __restrict__ bin_base,
    float4* __restrict__ payload,
    int n, int qpb)
{
    __shared__ float sxs[3][G];
    __shared__ unsigned int base[NBINS];
    const int tid = threadIdx.x, blk = blockIdx.x;

    stage_grids(xs0, xs1, xs2, sxs, tid, 256);
    for (int i = tid; i < NBINS; i += 256)
        base[i] = bin_base[i] + offs[(size_t)blk * NBINS + i];
    __syncthreads();

    const int q0 = blk * qpb, q1 = min(n, q0 + qpb);
    for (int q = q0 + tid; q < q1; q += 256) {
        int li0, li1, li2; float t0, t1, t2;
        search1(sxs[0], x[q * 3 + 0], li0, t0);
        search1(sxs[1], x[q * 3 + 1], li1, t1);
        search1(sxs[2], x[q * 3 + 2], li2, t2);
        unsigned int slot = atomicAdd(&base[bin_of(li0, li1, li2)], 1u);
        const unsigned int bits = (unsigned int)q
                                | ((unsigned int)(li0 & 7) << 20)
                                | ((unsigned int)(li1 & 7) << 23)
                                | ((unsigned int)(li2 & 7) << 26);
        payload[slot] = make_float4(t0, t1, t2, __uint_as_float(bits));
    }
}

// ---------- pass 4: lean chunked gather (no LDS, no search, no cells) ----------
// One block = one 64-query chunk of one bin. Bin is block-uniform.

__global__ __launch_bounds__(256) void interp_chunk_kernel(
    const float4* __restrict__ payload,
    const float* __restrict__ y,
    const unsigned int* __restrict__ bin_base,
    const unsigned int* __restrict__ map,
    const unsigned int* __restrict__ nchunks,
    float* __restrict__ out)
{
    // XCD-aware swizzle (MAXCHUNK % 8 == 0); map is bin-ordered so each
    // swizzle class gets a spatially-contiguous range of bins.
    int bid = blockIdx.x;
    bid = (bid & 7) * (MAXCHUNK >> 3) + (bid >> 3);
    if ((unsigned int)bid >= nchunks[0]) return;

    const unsigned int info = map[bid];
    const unsigned int bin  = info & 0xFFFu;
    const unsigned int chk  = info >> 12;
    const int o0 = (int)((bin >> 8) & 15u) << 3;
    const int o1 = (int)((bin >> 4) & 15u) << 3;
    const int o2 = (int)(bin & 15u) << 3;

    const unsigned int qs = bin_base[bin] + chk * QPB;
    const unsigned int qe = min(bin_base[bin + 1], qs + QPB);
    const unsigned int i  = qs + (threadIdx.x >> 2);
    if (i >= qe) return;
    const int cg = (threadIdx.x & 3) << 2;

    const float4 p = payload[i];
    const unsigned int bits = __float_as_uint(p.w);
    const unsigned int q = bits & 0xFFFFFu;
    const int c0 = o0 + (int)((bits >> 20) & 7u);
    const int c1 = o1 + (int)((bits >> 23) & 7u);
    const int c2 = o2 + (int)((bits >> 26) & 7u);

    const float t0 = p.x, t1 = p.y, t2 = p.z;
    const float u0 = 1.f - t0, u1 = 1.f - t1, u2 = 1.f - t2;

    const float* yb = y + (size_t)((((c0 << 7) | c1) << 7) | c2) * D_OUT + cg;
    const f32x4 v000 = *(const f32x4*)(yb);
    const f32x4 v001 = *(const f32x4*)(yb + D_OUT);
    const f32x4 v010 = *(const f32x4*)(yb + G * D_OUT);
    const f32x4 v011 = *(const f32x4*)(yb + G * D_OUT + D_OUT);
    const f32x4 v100 = *(const f32x4*)(yb + G * G * D_OUT);
    const f32x4 v101 = *(const f32x4*)(yb + G * G * D_OUT + D_OUT);
    const f32x4 v110 = *(const f32x4*)(yb + G * G * D_OUT + G * D_OUT);
    const f32x4 v111 = *(const f32x4*)(yb + G * G * D_OUT + G * D_OUT + D_OUT);

    const float w000 = u0 * u1 * u2, w001 = u0 * u1 * t2;
    const float w010 = u0 * t1 * u2, w011 = u0 * t1 * t2;
    const float w100 = t0 * u1 * u2, w101 = t0 * u1 * t2;
    const float w110 = t0 * t1 * u2, w111 = t0 * t1 * t2;

    f32x4 acc = w000 * v000 + w001 * v001 + w010 * v010 + w011 * v011
              + w100 * v100 + w101 * v101 + w110 * v110 + w111 * v111;

    __builtin_nontemporal_store(acc, (f32x4*)(out + (size_t)q * D_OUT + cg));
}

// ---------- fallback: direct kernel (known-good R1) ----------

__global__ __launch_bounds__(256) void interp3d_kernel(
    const float* __restrict__ x, const float* __restrict__ y,
    const float* __restrict__ xs0, const float* __restrict__ xs1, const float* __restrict__ xs2,
    float* __restrict__ out, int nquery)
{
    __shared__ float sxs[3][G];
    stage_grids(xs0, xs1, xs2, sxs, threadIdx.x, 256);
    __syncthreads();

    const int q = blockIdx.x * 64 + (threadIdx.x >> 2);
    if (q >= nquery) return;
    const int cg = (threadIdx.x & 3) * 4;

    int li[3]; float t[3];
    #pragma unroll
    for (int d = 0; d < 3; ++d) search1(sxs[d], x[q * 3 + d], li[d], t[d]);

    const float w0[3] = { 1.f - t[0], 1.f - t[1], 1.f - t[2] };
    const float w1[3] = { t[0], t[1], t[2] };

    float4 acc = make_float4(0.f, 0.f, 0.f, 0.f);
    #pragma unroll
    for (int e = 0; e < 8; ++e) {
        const int e0 = (e >> 2) & 1, e1 = (e >> 1) & 1, e2 = e & 1;
        const float w = (e0 ? w1[0] : w0[0]) * (e1 ? w1[1] : w0[1]) * (e2 ? w1[2] : w0[2]);
        const int idx = ((li[0] + e0) * G + (li[1] + e1)) * G + (li[2] + e2);
        const float4 v = *(const float4*)(y + (size_t)idx * D_OUT + cg);
        acc.x += w * v.x; acc.y += w * v.y; acc.z += w * v.z; acc.w += w * v.w;
    }
    *(float4*)(out + (size_t)q * D_OUT + cg) = acc;
}

extern "C" void kernel_launch(void* const* d_in, const int* in_sizes, int n_in,
                              void* d_out, int out_size, void* d_ws, size_t ws_size,
                              hipStream_t stream) {
    const float* x   = (const float*)d_in[0];
    const float* y   = (const float*)d_in[1];
    const float* xs0 = (const float*)d_in[2];
    const float* xs1 = (const float*)d_in[3];
    const float* xs2 = (const float*)d_in[4];
    float* out = (float*)d_out;

    const int nquery = in_sizes[0] / 3;

    const size_t counts_elems = (size_t)NBLK * NBINS;
    const size_t need = (size_t)nquery * sizeof(float4)
                      + (2 * counts_elems + NBINS + (NBINS + 1) + MAXCHUNK + 16) * sizeof(unsigned int);
    if (ws_size < need || nquery > (1 << 20)) {
        const int blocks = (nquery + 63) / 64;
        hipLaunchKernelGGL(interp3d_kernel, dim3(blocks), dim3(256), 0, stream,
                           x, y, xs0, xs1, xs2, out, nquery);
        return;
    }

    float4*       payload  = (float4*)d_ws;
    unsigned int* counts   = (unsigned int*)(payload + nquery);
    unsigned int* offs     = counts + counts_elems;
    unsigned int* totals   = offs + counts_elems;
    unsigned int* bin_base = totals + NBINS;
    unsigned int* map      = bin_base + (NBINS + 1);
    unsigned int* nchunks  = map + MAXCHUNK;

    const int qpb = (nquery + NBLK - 1) / NBLK;

    hipLaunchKernelGGL(hist_kernel, dim3(NBLK), dim3(256), 0, stream,
                       x, xs0, xs1, xs2, counts, nquery, qpb);
    hipLaunchKernelGGL(scan_block_kernel, dim3(NBINS), dim3(NBLK), 0, stream,
                       counts, offs, totals);
    hipLaunchKernelGGL(scan_totals_kernel, dim3(1), dim3(1024), 0, stream,
                       totals, bin_base, map, nchunks);
    hipLaunchKernelGGL(scatter_kernel, dim3(NBLK), dim3(256), 0, stream,
                       x, xs0, xs1, xs2, offs, bin_base, payload, nquery, qpb);
    hipLaunchKernelGGL(interp_chunk_kernel, dim3(MAXCHUNK), dim3(256), 0, stream,
                       payload, y, bin_base, map, nchunks, out);
}

// Round 11
// 91.343 us; speedup vs baseline: 1.4613x; 1.1398x over previous
//
#include <hip/hip_runtime.h>

#define G 128
#define D_OUT 16
#define BIN_SHIFT 3              // 8 cells per bin per dim
#define NBINS (16 * 16 * 16)     // 4096
#define NBLK 256                 // blocks for hist/scatter passes

typedef float f32x4 __attribute__((ext_vector_type(4)));

// ---------- shared helpers ----------

__device__ __forceinline__ void stage_grids(const float* __restrict__ xs0,
                                            const float* __restrict__ xs1,
                                            const float* __restrict__ xs2,
                                            float (*sxs)[G], int tid, int nthreads)
{
    for (int i = tid; i < 3 * G; i += nthreads) {
        float v;
        if (i < G)            v = xs0[i];
        else if (i < 2 * G)   v = xs1[i - G];
        else                  v = xs2[i - 2 * G];
        (&sxs[0][0])[i] = v;
    }
}

__device__ __forceinline__ void search1(const float* __restrict__ g, float v,
                                        int& li, float& t)
{
    v = fminf(fmaxf(v, g[0]), g[G - 1]);
    int idx = 0;
    #pragma unroll
    for (int s = 64; s >= 1; s >>= 1) {
        int cand = idx + s;
        if (g[cand] <= v) idx = cand;
    }
    if (idx > G - 2) idx = G - 2;
    li = idx;
    t  = (v - g[idx]) / (g[idx + 1] - g[idx]);
}

__device__ __forceinline__ int bin_of(int li0, int li1, int li2)
{
    return ((li0 >> BIN_SHIFT) << 8) | ((li1 >> BIN_SHIFT) << 4) | (li2 >> BIN_SHIFT);
}

// ---------- pass 1: per-block LDS histogram ----------

__global__ __launch_bounds__(256) void hist_kernel(
    const float* __restrict__ x,
    const float* __restrict__ xs0, const float* __restrict__ xs1, const float* __restrict__ xs2,
    unsigned int* __restrict__ counts,   // [NBLK][NBINS]
    int n, int qpb)
{
    __shared__ float sxs[3][G];
    __shared__ unsigned int hist[NBINS];
    const int tid = threadIdx.x, blk = blockIdx.x;

    stage_grids(xs0, xs1, xs2, sxs, tid, 256);
    for (int i = tid; i < NBINS; i += 256) hist[i] = 0u;
    __syncthreads();

    const int q0 = blk * qpb, q1 = min(n, q0 + qpb);
    for (int q = q0 + tid; q < q1; q += 256) {
        int li[3]; float t;
        #pragma unroll
        for (int d = 0; d < 3; ++d) search1(sxs[d], x[q * 3 + d], li[d], t);
        atomicAdd(&hist[bin_of(li[0], li[1], li[2])], 1u);
    }
    __syncthreads();

    for (int i = tid; i < NBINS; i += 256)
        counts[(size_t)blk * NBINS + i] = hist[i];
}

// ---------- pass 2a: per-bin exclusive scan across block rows ----------

__global__ __launch_bounds__(256) void scan_block_kernel(
    const unsigned int* __restrict__ counts,
    unsigned int* __restrict__ offs,
    unsigned int* __restrict__ totals)
{
    __shared__ unsigned int sd[NBLK];
    const int b = blockIdx.x, k = threadIdx.x;
    const unsigned int v = counts[(size_t)k * NBINS + b];
    sd[k] = v;
    __syncthreads();
    for (int off = 1; off < NBLK; off <<= 1) {
        unsigned int t = sd[k];
        unsigned int a = (k >= off) ? sd[k - off] : 0u;
        __syncthreads();
        sd[k] = t + a;
        __syncthreads();
    }
    const unsigned int incl = sd[k];
    offs[(size_t)k * NBINS + b] = incl - v;
    if (k == NBLK - 1) totals[b] = incl;
}

// ---------- pass 2b: exclusive scan over 4096 bin totals ----------

__global__ __launch_bounds__(1024) void scan_totals_kernel(
    const unsigned int* __restrict__ totals, unsigned int* __restrict__ bin_base)
{
    __shared__ unsigned int sd[1024];
    const int t = threadIdx.x;
    uint4 c = ((const uint4*)totals)[t];
    unsigned int s = c.x + c.y + c.z + c.w;
    sd[t] = s;
    __syncthreads();
    for (int off = 1; off < 1024; off <<= 1) {
        unsigned int v = sd[t];
        unsigned int add = (t >= off) ? sd[t - off] : 0u;
        __syncthreads();
        sd[t] = v + add;
        __syncthreads();
    }
    unsigned int excl = sd[t] - s;
    uint4 o;
    o.x = excl;
    o.y = o.x + c.x;
    o.z = o.y + c.y;
    o.w = o.z + c.z;
    ((uint4*)bin_base)[t] = o;
}

// ---------- pass 3: scatter; payload = {t0|t1<<16 (u16), t2 (u16), cell, q} ----------

__global__ __launch_bounds__(256) void scatter_kernel(
    const float* __restrict__ x,
    const float* __restrict__ xs0, const float* __restrict__ xs1, const float* __restrict__ xs2,
    const unsigned int* __restrict__ offs,
    const unsigned int* __restrict__ bin_base,
    uint4* __restrict__ payload,
    int n, int qpb)
{
    __shared__ float sxs[3][G];
    __shared__ unsigned int base[NBINS];
    const int tid = threadIdx.x, blk = blockIdx.x;

    stage_grids(xs0, xs1, xs2, sxs, tid, 256);
    for (int i = tid; i < NBINS; i += 256)
        base[i] = bin_base[i] + offs[(size_t)blk * NBINS + i];
    __syncthreads();

    const int q0 = blk * qpb, q1 = min(n, q0 + qpb);
    for (int q = q0 + tid; q < q1; q += 256) {
        int li0, li1, li2; float t0, t1, t2;
        search1(sxs[0], x[q * 3 + 0], li0, t0);
        search1(sxs[1], x[q * 3 + 1], li1, t1);
        search1(sxs[2], x[q * 3 + 2], li2, t2);
        unsigned int slot = atomicAdd(&base[bin_of(li0, li1, li2)], 1u);
        uint4 pl;
        pl.x = __float2uint_rn(t0 * 65535.f) | (__float2uint_rn(t1 * 65535.f) << 16);
        pl.y = __float2uint_rn(t2 * 65535.f);
        pl.z = (unsigned int)((((li0 << 7) | li1) << 7) | li2);   // 21-bit cell
        pl.w = (unsigned int)q;
        payload[slot] = pl;
    }
}

// ---------- pass 4: leanest gather over the bin-sorted dense stream ----------

__global__ __launch_bounds__(256) void interp_gather_kernel(
    const uint4* __restrict__ payload,
    const float* __restrict__ y,
    float* __restrict__ out, int n)
{
    // XCD-aware swizzle: consecutive sorted chunks stay on one XCD's L2.
    int bid = blockIdx.x;
    int nb  = gridDim.x;
    if ((nb & 7) == 0) {
        int chunk = nb >> 3;
        bid = (bid & 7) * chunk + (bid >> 3);
    }

    const int i = bid * 64 + (threadIdx.x >> 2);
    if (i >= n) return;
    const int cg = (threadIdx.x & 3) << 2;

    const uint4 p = payload[i];
    const float s = 1.f / 65535.f;
    const float t0 = (float)(p.x & 0xFFFFu) * s;
    const float t1 = (float)(p.x >> 16) * s;
    const float t2 = (float)(p.y & 0xFFFFu) * s;
    const float u0 = 1.f - t0, u1 = 1.f - t1, u2 = 1.f - t2;

    const float* yb = y + (size_t)p.z * D_OUT + cg;
    const f32x4 v000 = *(const f32x4*)(yb);
    const f32x4 v001 = *(const f32x4*)(yb + D_OUT);
    const f32x4 v010 = *(const f32x4*)(yb + G * D_OUT);
    const f32x4 v011 = *(const f32x4*)(yb + G * D_OUT + D_OUT);
    const f32x4 v100 = *(const f32x4*)(yb + G * G * D_OUT);
    const f32x4 v101 = *(const f32x4*)(yb + G * G * D_OUT + D_OUT);
    const f32x4 v110 = *(const f32x4*)(yb + G * G * D_OUT + G * D_OUT);
    const f32x4 v111 = *(const f32x4*)(yb + G * G * D_OUT + G * D_OUT + D_OUT);

    const float w000 = u0 * u1 * u2, w001 = u0 * u1 * t2;
    const float w010 = u0 * t1 * u2, w011 = u0 * t1 * t2;
    const float w100 = t0 * u1 * u2, w101 = t0 * u1 * t2;
    const float w110 = t0 * t1 * u2, w111 = t0 * t1 * t2;

    f32x4 acc = w000 * v000 + w001 * v001 + w010 * v010 + w011 * v011
              + w100 * v100 + w101 * v101 + w110 * v110 + w111 * v111;

    __builtin_nontemporal_store(acc, (f32x4*)(out + (size_t)p.w * D_OUT + cg));
}

// ---------- fallback: direct kernel (known-good R1) ----------

__global__ __launch_bounds__(256) void interp3d_kernel(
    const float* __restrict__ x, const float* __restrict__ y,
    const float* __restrict__ xs0, const float* __restrict__ xs1, const float* __restrict__ xs2,
    float* __restrict__ out, int nquery)
{
    __shared__ float sxs[3][G];
    stage_grids(xs0, xs1, xs2, sxs, threadIdx.x, 256);
    __syncthreads();

    const int q = blockIdx.x * 64 + (threadIdx.x >> 2);
    if (q >= nquery) return;
    const int cg = (threadIdx.x & 3) * 4;

    int li[3]; float t[3];
    #pragma unroll
    for (int d = 0; d < 3; ++d) search1(sxs[d], x[q * 3 + d], li[d], t[d]);

    const float w0[3] = { 1.f - t[0], 1.f - t[1], 1.f - t[2] };
    const float w1[3] = { t[0], t[1], t[2] };

    float4 acc = make_float4(0.f, 0.f, 0.f, 0.f);
    #pragma unroll
    for (int e = 0; e < 8; ++e) {
        const int e0 = (e >> 2) & 1, e1 = (e >> 1) & 1, e2 = e & 1;
        const float w = (e0 ? w1[0] : w0[0]) * (e1 ? w1[1] : w0[1]) * (e2 ? w1[2] : w0[2]);
        const int idx = ((li[0] + e0) * G + (li[1] + e1)) * G + (li[2] + e2);
        const float4 v = *(const float4*)(y + (size_t)idx * D_OUT + cg);
        acc.x += w * v.x; acc.y += w * v.y; acc.z += w * v.z; acc.w += w * v.w;
    }
    *(float4*)(out + (size_t)q * D_OUT + cg) = acc;
}

extern "C" void kernel_launch(void* const* d_in, const int* in_sizes, int n_in,
                              void* d_out, int out_size, void* d_ws, size_t ws_size,
                              hipStream_t stream) {
    const float* x   = (const float*)d_in[0];
    const float* y   = (const float*)d_in[1];
    const float* xs0 = (const float*)d_in[2];
    const float* xs1 = (const float*)d_in[3];
    const float* xs2 = (const float*)d_in[4];
    float* out = (float*)d_out;

    const int nquery = in_sizes[0] / 3;

    const size_t counts_elems = (size_t)NBLK * NBINS;
    const size_t need = (size_t)nquery * sizeof(uint4)
                      + (2 * counts_elems + 2 * NBINS + 16) * sizeof(unsigned int);
    if (ws_size < need || nquery > (1 << 20)) {
        const int blocks = (nquery + 63) / 64;
        hipLaunchKernelGGL(interp3d_kernel, dim3(blocks), dim3(256), 0, stream,
                           x, y, xs0, xs1, xs2, out, nquery);
        return;
    }

    uint4*        payload  = (uint4*)d_ws;
    unsigned int* counts   = (unsigned int*)(payload + nquery);
    unsigned int* offs     = counts + counts_elems;
    unsigned int* totals   = offs + counts_elems;
    unsigned int* bin_base = totals + NBINS;

    const int qpb = (nquery + NBLK - 1) / NBLK;

    hipLaunchKernelGGL(hist_kernel, dim3(NBLK), dim3(256), 0, stream,
                       x, xs0, xs1, xs2, counts, nquery, qpb);
    hipLaunchKernelGGL(scan_block_kernel, dim3(NBINS), dim3(NBLK), 0, stream,
                       counts, offs, totals);
    hipLaunchKernelGGL(scan_totals_kernel, dim3(1), dim3(1024), 0, stream,
                       totals, bin_base);
    hipLaunchKernelGGL(scatter_kernel, dim3(NBLK), dim3(256), 0, stream,
                       x, xs0, xs1, xs2, offs, bin_base, payload, nquery, qpb);

    const int b64 = (nquery + 63) / 64;
    hipLaunchKernelGGL(interp_gather_kernel, dim3(b64), dim3(256), 0, stream,
                       payload, y, out, nquery);
}